// Round 1
// baseline (390.024 us; speedup 1.0000x reference)
//
#include <hip/hip_runtime.h>
#include <stdint.h>

#define N_Q    4096
#define D_K    512
#define D_OUT  16384
#define NCLUST 256

#define BM 128
#define BN 128
#define BK 32

typedef __attribute__((ext_vector_type(4))) float f32x4;
typedef __attribute__((ext_vector_type(8))) short bf16x8;

// round-to-nearest-even f32 -> bf16 (inputs are finite; no NaN handling needed)
__device__ __forceinline__ ushort f2bf(float f) {
  uint32_t u = __float_as_uint(f);
  u += 0x7FFFu + ((u >> 16) & 1u);
  return (ushort)(u >> 16);
}

// width-16 global->LDS async copy; lds base must be wave-uniform, HW adds lane*16
#define GLOAD_LDS16(g, l)                                         \
  __builtin_amdgcn_global_load_lds(                               \
      (const __attribute__((address_space(1))) void*)(g),         \
      (__attribute__((address_space(3))) void*)(l), 16, 0, 0)

__global__ __launch_bounds__(256) void cvt_bf16_kernel(const float* __restrict__ src,
                                                       ushort* __restrict__ dst, int n8) {
  int i = blockIdx.x * 256 + threadIdx.x;
  if (i >= n8) return;
  const float4* s = reinterpret_cast<const float4*>(src) + (size_t)i * 2;
  float4 v0 = s[0], v1 = s[1];
  uint4 o;
  o.x = (uint32_t)f2bf(v0.x) | ((uint32_t)f2bf(v0.y) << 16);
  o.y = (uint32_t)f2bf(v0.z) | ((uint32_t)f2bf(v0.w) << 16);
  o.z = (uint32_t)f2bf(v1.x) | ((uint32_t)f2bf(v1.y) << 16);
  o.w = (uint32_t)f2bf(v1.z) | ((uint32_t)f2bf(v1.w) << 16);
  reinterpret_cast<uint4*>(dst)[i] = o;
}

// One block per query row; thread t owns centroid t. f32 throughout (boolean safety).
__global__ __launch_bounds__(256) void routing_kernel(const float* __restrict__ input,
                                                      const float* __restrict__ cent,
                                                      float* __restrict__ qmask,
                                                      float* __restrict__ cmask) {
  __shared__ float4 rowv[D_K / 4];
  __shared__ float red[256];
  int q = blockIdx.x, t = threadIdx.x;
  if (t < D_K / 4) rowv[t] = reinterpret_cast<const float4*>(input + (size_t)q * D_K)[t];
  __syncthreads();

  const float4* cv = reinterpret_cast<const float4*>(cent + (size_t)t * D_K);
  float acc = 0.f;
#pragma unroll 4
  for (int k = 0; k < D_K / 4; ++k) {
    float4 c = cv[k], r = rowv[k];
    acc += c.x * r.x + c.y * r.y + c.z * r.z + c.w * r.w;
  }
  float logit = acc * 10.0f;  // divide by TEMPERATURE=0.1

  red[t] = logit; __syncthreads();
#pragma unroll
  for (int s = 128; s > 0; s >>= 1) { if (t < s) red[t] = fmaxf(red[t], red[t + s]); __syncthreads(); }
  float m = red[0]; __syncthreads();

  float e = expf(logit - m);
  red[t] = e; __syncthreads();
#pragma unroll
  for (int s = 128; s > 0; s >>= 1) { if (t < s) red[t] += red[t + s]; __syncthreads(); }
  float p = e / red[0];
  bool act = p > 0.01f;
  if (act) cmask[t] = 1.0f;   // benign race: everyone writes 1.0
  __syncthreads();

  red[t] = act ? 1.f : 0.f; __syncthreads();
#pragma unroll
  for (int s = 128; s > 0; s >>= 1) { if (t < s) red[t] = fmaxf(red[t], red[t + s]); __syncthreads(); }
  if (t == 0) qmask[q] = red[0];
}

// Masked bf16 GEMM, m97 structure: 128x128 tile, BK=32, 4 waves (2x2), each wave 64x64
// via 4x4 grid of 16x16x32 MFMA. global_load_lds width=16, linear LDS layout.
__global__ __launch_bounds__(256) void gemm_masked_kernel(
    const ushort* __restrict__ A,      // [N_Q][D_K] bf16
    const ushort* __restrict__ W,      // [D_OUT][D_K] bf16 (already B^T layout)
    const float* __restrict__ bias,    // [D_OUT]
    const int* __restrict__ assign,    // [D_OUT]
    const float* __restrict__ qmask,   // [N_Q]  {0,1}
    const float* __restrict__ cmask,   // [NCLUST] {0,1}
    float* __restrict__ C) {           // [N_Q][D_OUT]
  __shared__ ushort sA[BM * BK];  // 8 KiB
  __shared__ ushort sB[BN * BK];  // 8 KiB

  int tid = threadIdx.x;
  int wave = tid >> 6, lane = tid & 63;

  // XCD-aware swizzle: 4096 blocks, 8 XCDs, 512 per XCD (4096 % 8 == 0 -> bijective)
  int bid = blockIdx.x;
  int swz = (bid & 7) * 512 + (bid >> 3);
  int ntile = swz & 127;   // D_OUT/BN = 128
  int mtile = swz >> 7;    // N_Q/BM  = 32
  int m0 = mtile * BM, n0 = ntile * BN;

  int wr = wave >> 1, wc = wave & 1;  // wave -> 64x64 quadrant

  f32x4 acc[4][4] = {};

  const ushort* gA = A + (size_t)m0 * D_K;
  const ushort* gB = W + (size_t)n0 * D_K;

  for (int kt = 0; kt < D_K; kt += BK) {
#pragma unroll
    for (int p = 0; p < 2; ++p) {
      int row = p * 64 + wave * 16 + (lane >> 2);
      int kc = (lane & 3) * 8;
      GLOAD_LDS16(gA + (size_t)row * D_K + kt + kc, sA + p * 2048 + wave * 512);
      GLOAD_LDS16(gB + (size_t)row * D_K + kt + kc, sB + p * 2048 + wave * 512);
    }
    __syncthreads();  // drains vmcnt; tiles visible

    bf16x8 a[4], b[4];
    int arow = wr * 64 + (lane & 15);
    int brow = wc * 64 + (lane & 15);
    int kq = (lane >> 4) * 8;
#pragma unroll
    for (int i = 0; i < 4; ++i)
      a[i] = *reinterpret_cast<const bf16x8*>(&sA[(arow + i * 16) * BK + kq]);
#pragma unroll
    for (int j = 0; j < 4; ++j)
      b[j] = *reinterpret_cast<const bf16x8*>(&sB[(brow + j * 16) * BK + kq]);
#pragma unroll
    for (int i = 0; i < 4; ++i)
#pragma unroll
      for (int j = 0; j < 4; ++j)
        acc[i][j] = __builtin_amdgcn_mfma_f32_16x16x32_bf16(a[i], b[j], acc[i][j], 0, 0, 0);
    __syncthreads();  // before next stage overwrites LDS
  }

  // epilogue: C/D layout col=lane&15, row=(lane>>4)*4+reg
  float qm[4][4];
#pragma unroll
  for (int i = 0; i < 4; ++i) {
    int rbase = m0 + wr * 64 + i * 16 + (lane >> 4) * 4;
#pragma unroll
    for (int r = 0; r < 4; ++r) qm[i][r] = qmask[rbase + r];
  }
#pragma unroll
  for (int j = 0; j < 4; ++j) {
    int col = n0 + wc * 64 + j * 16 + (lane & 15);
    float bj = bias[col];
    float rm = cmask[assign[col]];
#pragma unroll
    for (int i = 0; i < 4; ++i) {
      int rbase = m0 + wr * 64 + i * 16 + (lane >> 4) * 4;
#pragma unroll
      for (int r = 0; r < 4; ++r) {
        C[(size_t)(rbase + r) * D_OUT + col] = (acc[i][j][r] + bj) * qm[i][r] * rm;
      }
    }
  }
}

extern "C" void kernel_launch(void* const* d_in, const int* in_sizes, int n_in,
                              void* d_out, int out_size, void* d_ws, size_t ws_size,
                              hipStream_t stream) {
  const float* input     = (const float*)d_in[0];  // [4096,512]
  const float* weight    = (const float*)d_in[1];  // [16384,512]
  const float* bias      = (const float*)d_in[2];  // [16384]
  const float* centroids = (const float*)d_in[3];  // [256,512]
  const int*   assign    = (const int*)d_in[4];    // [16384]
  float* out = (float*)d_out;

  // workspace layout (bytes):
  //   A_bf16: 4096*512*2   = 4,194,304
  //   W_bf16: 16384*512*2  = 16,777,216
  //   qmask : 4096*4       = 16,384
  //   cmask : 256*4        = 1,024
  char* ws = (char*)d_ws;
  ushort* A_bf  = (ushort*)ws;
  ushort* W_bf  = (ushort*)(ws + 4194304);
  float*  qmask = (float*)(ws + 20971520);
  float*  cmask = (float*)(ws + 20987904);

  hipMemsetAsync(cmask, 0, NCLUST * sizeof(float), stream);

  cvt_bf16_kernel<<<(N_Q * D_K / 8 + 255) / 256, 256, 0, stream>>>(input, A_bf, N_Q * D_K / 8);
  cvt_bf16_kernel<<<(D_OUT * D_K / 8 + 255) / 256, 256, 0, stream>>>(weight, W_bf, D_OUT * D_K / 8);
  routing_kernel<<<N_Q, 256, 0, stream>>>(input, centroids, qmask, cmask);
  gemm_masked_kernel<<<(N_Q / BM) * (D_OUT / BN), 256, 0, stream>>>(
      A_bf, W_bf, bias, assign, qmask, cmask, out);
}

// Round 2
// 211.385 us; speedup vs baseline: 1.8451x; 1.8451x over previous
//
#include <hip/hip_runtime.h>
#include <stdint.h>

#define N_Q    4096
#define D_K    512
#define D_OUT  16384
#define NCLUST 256

#define BM 128
#define BN 128
#define BK 32

typedef __attribute__((ext_vector_type(4))) float f32x4;
typedef __attribute__((ext_vector_type(8))) short bf16x8;

// round-to-nearest-even f32 -> bf16
__device__ __forceinline__ ushort f2bf(float f) {
  uint32_t u = __float_as_uint(f);
  u += 0x7FFFu + ((u >> 16) & 1u);
  return (ushort)(u >> 16);
}

#define GLOAD_LDS16(g, l)                                         \
  __builtin_amdgcn_global_load_lds(                               \
      (const __attribute__((address_space(1))) void*)(g),         \
      (__attribute__((address_space(3))) void*)(l), 16, 0, 0)

__global__ __launch_bounds__(256) void cvt_bf16_kernel(const float* __restrict__ src,
                                                       ushort* __restrict__ dst, int n8) {
  int i = blockIdx.x * 256 + threadIdx.x;
  if (i >= n8) return;
  const float4* s = reinterpret_cast<const float4*>(src) + (size_t)i * 2;
  float4 v0 = s[0], v1 = s[1];
  uint4 o;
  o.x = (uint32_t)f2bf(v0.x) | ((uint32_t)f2bf(v0.y) << 16);
  o.y = (uint32_t)f2bf(v0.z) | ((uint32_t)f2bf(v0.w) << 16);
  o.z = (uint32_t)f2bf(v1.x) | ((uint32_t)f2bf(v1.y) << 16);
  o.w = (uint32_t)f2bf(v1.z) | ((uint32_t)f2bf(v1.w) << 16);
  reinterpret_cast<uint4*>(dst)[i] = o;
}

// centT4[k4][c] = float4{cent[c][4k4 .. 4k4+3]}  -> lane=c coalesced loads in routing
__global__ __launch_bounds__(256) void transpose_cent_kernel(const float* __restrict__ cent,
                                                             float4* __restrict__ centT4) {
  int idx = blockIdx.x * 256 + threadIdx.x;    // 256*128 = 32768
  int k4 = idx & 127, c = idx >> 7;            // consecutive tid -> consecutive k4: coalesced read
  float4 v = *reinterpret_cast<const float4*>(&cent[(size_t)c * D_K + k4 * 4]);
  centT4[(size_t)k4 * NCLUST + c] = v;
}

// 8 queries per block, thread t owns centroid c=t. Coalesced centT4 loads (L2/L3-hot),
// block-uniform query-row loads (scalar path). f32 throughout (threshold boolean safety).
__global__ __launch_bounds__(256) void routing_kernel(const float* __restrict__ input,
                                                      const float4* __restrict__ centT4,
                                                      float* __restrict__ qmask,
                                                      float* __restrict__ cmask) {
  __shared__ float lgs[8][NCLUST];
  int c = threadIdx.x;
  int q0 = blockIdx.x * 8;
  const float* __restrict__ inp = input + (size_t)q0 * D_K;

  float acc[8] = {0, 0, 0, 0, 0, 0, 0, 0};
  for (int k4 = 0; k4 < D_K / 4; ++k4) {
    float4 v = centT4[(size_t)k4 * NCLUST + c];
#pragma unroll
    for (int q = 0; q < 8; ++q) {
      float4 r = *reinterpret_cast<const float4*>(&inp[q * D_K + k4 * 4]);  // uniform addr
      acc[q] += v.x * r.x + v.y * r.y + v.z * r.z + v.w * r.w;
    }
  }
#pragma unroll
  for (int q = 0; q < 8; ++q) lgs[q][c] = acc[q] * 10.0f;  // /TEMPERATURE
  __syncthreads();

  int wave = c >> 6, lane = c & 63;
#pragma unroll
  for (int qq = 0; qq < 2; ++qq) {
    int q = wave * 2 + qq;
    float4 lv = *reinterpret_cast<const float4*>(&lgs[q][lane * 4]);
    float m = fmaxf(fmaxf(lv.x, lv.y), fmaxf(lv.z, lv.w));
#pragma unroll
    for (int off = 32; off > 0; off >>= 1) m = fmaxf(m, __shfl_xor(m, off));
    float e0 = expf(lv.x - m), e1 = expf(lv.y - m), e2 = expf(lv.z - m), e3 = expf(lv.w - m);
    float s = e0 + e1 + e2 + e3;
#pragma unroll
    for (int off = 32; off > 0; off >>= 1) s += __shfl_xor(s, off);
    float thr = 0.01f * s;  // p > 0.01  <=>  e > 0.01*s
    bool a0 = e0 > thr, a1 = e1 > thr, a2 = e2 > thr, a3 = e3 > thr;
    if (a0) cmask[lane * 4 + 0] = 1.0f;  // benign races: all writers store 1.0
    if (a1) cmask[lane * 4 + 1] = 1.0f;
    if (a2) cmask[lane * 4 + 2] = 1.0f;
    if (a3) cmask[lane * 4 + 3] = 1.0f;
    unsigned long long any = __ballot(a0 | a1 | a2 | a3);
    if (lane == 0) qmask[q0 + q] = any ? 1.0f : 0.0f;
  }
}

// Masked bf16 GEMM, m97 structure (unchanged from round 1; passed, ~<=110us).
__global__ __launch_bounds__(256) void gemm_masked_kernel(
    const ushort* __restrict__ A, const ushort* __restrict__ W,
    const float* __restrict__ bias, const int* __restrict__ assign,
    const float* __restrict__ qmask, const float* __restrict__ cmask,
    float* __restrict__ C) {
  __shared__ ushort sA[BM * BK];
  __shared__ ushort sB[BN * BK];

  int tid = threadIdx.x;
  int wave = tid >> 6, lane = tid & 63;

  int bid = blockIdx.x;
  int swz = (bid & 7) * 512 + (bid >> 3);   // 4096 % 8 == 0 -> bijective
  int ntile = swz & 127;
  int mtile = swz >> 7;
  int m0 = mtile * BM, n0 = ntile * BN;

  int wr = wave >> 1, wc = wave & 1;

  f32x4 acc[4][4] = {};

  const ushort* gA = A + (size_t)m0 * D_K;
  const ushort* gB = W + (size_t)n0 * D_K;

  for (int kt = 0; kt < D_K; kt += BK) {
#pragma unroll
    for (int p = 0; p < 2; ++p) {
      int row = p * 64 + wave * 16 + (lane >> 2);
      int kc = (lane & 3) * 8;
      GLOAD_LDS16(gA + (size_t)row * D_K + kt + kc, sA + p * 2048 + wave * 512);
      GLOAD_LDS16(gB + (size_t)row * D_K + kt + kc, sB + p * 2048 + wave * 512);
    }
    __syncthreads();

    bf16x8 a[4], b[4];
    int arow = wr * 64 + (lane & 15);
    int brow = wc * 64 + (lane & 15);
    int kq = (lane >> 4) * 8;
#pragma unroll
    for (int i = 0; i < 4; ++i)
      a[i] = *reinterpret_cast<const bf16x8*>(&sA[(arow + i * 16) * BK + kq]);
#pragma unroll
    for (int j = 0; j < 4; ++j)
      b[j] = *reinterpret_cast<const bf16x8*>(&sB[(brow + j * 16) * BK + kq]);
#pragma unroll
    for (int i = 0; i < 4; ++i)
#pragma unroll
      for (int j = 0; j < 4; ++j)
        acc[i][j] = __builtin_amdgcn_mfma_f32_16x16x32_bf16(a[i], b[j], acc[i][j], 0, 0, 0);
    __syncthreads();
  }

  float qm[4][4];
#pragma unroll
  for (int i = 0; i < 4; ++i) {
    int rbase = m0 + wr * 64 + i * 16 + (lane >> 4) * 4;
#pragma unroll
    for (int r = 0; r < 4; ++r) qm[i][r] = qmask[rbase + r];
  }
#pragma unroll
  for (int j = 0; j < 4; ++j) {
    int col = n0 + wc * 64 + j * 16 + (lane & 15);
    float bj = bias[col];
    float rm = cmask[assign[col]];
#pragma unroll
    for (int i = 0; i < 4; ++i) {
      int rbase = m0 + wr * 64 + i * 16 + (lane >> 4) * 4;
#pragma unroll
      for (int r = 0; r < 4; ++r) {
        C[(size_t)(rbase + r) * D_OUT + col] = (acc[i][j][r] + bj) * qm[i][r] * rm;
      }
    }
  }
}

extern "C" void kernel_launch(void* const* d_in, const int* in_sizes, int n_in,
                              void* d_out, int out_size, void* d_ws, size_t ws_size,
                              hipStream_t stream) {
  const float* input     = (const float*)d_in[0];
  const float* weight    = (const float*)d_in[1];
  const float* bias      = (const float*)d_in[2];
  const float* centroids = (const float*)d_in[3];
  const int*   assign    = (const int*)d_in[4];
  float* out = (float*)d_out;

  // ws layout (bytes):
  //   A_bf16 : 0          .. 4,194,304
  //   W_bf16 : 4,194,304  .. 20,971,520
  //   qmask  : 20,971,520 (16 KB)
  //   cmask  : 20,987,904 (1 KB)
  //   centT4 : 21,000,192 (512 KB)
  char* ws = (char*)d_ws;
  ushort* A_bf   = (ushort*)ws;
  ushort* W_bf   = (ushort*)(ws + 4194304);
  float*  qmask  = (float*)(ws + 20971520);
  float*  cmask  = (float*)(ws + 20987904);
  float4* centT4 = (float4*)(ws + 21000192);

  hipMemsetAsync(cmask, 0, NCLUST * sizeof(float), stream);

  cvt_bf16_kernel<<<(N_Q * D_K / 8 + 255) / 256, 256, 0, stream>>>(input, A_bf, N_Q * D_K / 8);
  cvt_bf16_kernel<<<(D_OUT * D_K / 8 + 255) / 256, 256, 0, stream>>>(weight, W_bf, D_OUT * D_K / 8);
  transpose_cent_kernel<<<128, 256, 0, stream>>>(centroids, centT4);
  routing_kernel<<<N_Q / 8, 256, 0, stream>>>(input, centT4, qmask, cmask);
  gemm_masked_kernel<<<(N_Q / BM) * (D_OUT / BN), 256, 0, stream>>>(
      A_bf, W_bf, bias, assign, qmask, cmask, out);
}

// Round 3
// 164.927 us; speedup vs baseline: 2.3648x; 1.2817x over previous
//
#include <hip/hip_runtime.h>
#include <stdint.h>

#define N_Q    4096
#define D_K    512
#define D_OUT  16384
#define NCLUST 256

// GEMM geometry: 256x256 tile, BK=32, 8 waves (2M x 4N), triple-buffered LDS ring
#define BM 256
#define BN 256
#define BK 32
#define NT (D_K / BK)   // 16 K-tiles

typedef __attribute__((ext_vector_type(4))) float f32x4;
typedef __attribute__((ext_vector_type(8))) short bf16x8;

// round-to-nearest-even f32 -> bf16
__device__ __forceinline__ uint32_t f2bf(float f) {
  uint32_t u = __float_as_uint(f);
  u += 0x7FFFu + ((u >> 16) & 1u);
  return u >> 16;
}

#define GLOAD_LDS16(g, l)                                         \
  __builtin_amdgcn_global_load_lds(                               \
      (const __attribute__((address_space(1))) void*)(g),         \
      (__attribute__((address_space(3))) void*)(l), 16, 0, 0)

// counted-vmcnt wait fused with barrier; memory clobber pins all LDS/global ops
#define WAIT_BAR(N) asm volatile("s_waitcnt vmcnt(" #N ")\n\ts_barrier" ::: "memory")

__global__ __launch_bounds__(256) void cvt_bf16_kernel(const float* __restrict__ src,
                                                       ushort* __restrict__ dst, int n8) {
  int i = blockIdx.x * 256 + threadIdx.x;
  if (i >= n8) return;
  const float4* s = reinterpret_cast<const float4*>(src) + (size_t)i * 2;
  float4 v0 = s[0], v1 = s[1];
  uint4 o;
  o.x = f2bf(v0.x) | (f2bf(v0.y) << 16);
  o.y = f2bf(v0.z) | (f2bf(v0.w) << 16);
  o.z = f2bf(v1.x) | (f2bf(v1.y) << 16);
  o.w = f2bf(v1.z) | (f2bf(v1.w) << 16);
  reinterpret_cast<uint4*>(dst)[i] = o;
}

// centT4[k4][c] transpose for coalesced routing loads; also zeroes cmask (block 0)
__global__ __launch_bounds__(256) void transpose_cent_kernel(const float* __restrict__ cent,
                                                             float4* __restrict__ centT4,
                                                             float* __restrict__ cmask) {
  if (blockIdx.x == 0) cmask[threadIdx.x] = 0.0f;
  int idx = blockIdx.x * 256 + threadIdx.x;
  int k4 = idx & 127, c = idx >> 7;
  float4 v = *reinterpret_cast<const float4*>(&cent[(size_t)c * D_K + k4 * 4]);
  centT4[(size_t)k4 * NCLUST + c] = v;
}

// 8 queries/block; thread t owns centroid t. Also converts its 8 input rows to bf16
// (fused cvt saves a dispatch). f32 routing math throughout (threshold booleans).
__global__ __launch_bounds__(256) void routing_kernel(const float* __restrict__ input,
                                                      const float4* __restrict__ centT4,
                                                      float* __restrict__ qmask,
                                                      float* __restrict__ cmask,
                                                      ushort* __restrict__ A_bf) {
  __shared__ float lgs[8][NCLUST];
  int c = threadIdx.x;
  int q0 = blockIdx.x * 8;
  const float* __restrict__ inp = input + (size_t)q0 * D_K;

  // fused A-convert: 8 rows * 512 = 4096 elems, 16 per thread
  {
    const float4* s4 = reinterpret_cast<const float4*>(inp) + c * 4;
    float4 x0 = s4[0], x1 = s4[1], x2 = s4[2], x3 = s4[3];
    uint4 o0, o1;
    o0.x = f2bf(x0.x) | (f2bf(x0.y) << 16);
    o0.y = f2bf(x0.z) | (f2bf(x0.w) << 16);
    o0.z = f2bf(x1.x) | (f2bf(x1.y) << 16);
    o0.w = f2bf(x1.z) | (f2bf(x1.w) << 16);
    o1.x = f2bf(x2.x) | (f2bf(x2.y) << 16);
    o1.y = f2bf(x2.z) | (f2bf(x2.w) << 16);
    o1.z = f2bf(x3.x) | (f2bf(x3.y) << 16);
    o1.w = f2bf(x3.z) | (f2bf(x3.w) << 16);
    uint4* dst = reinterpret_cast<uint4*>(A_bf + (size_t)q0 * D_K);
    dst[c * 2] = o0;
    dst[c * 2 + 1] = o1;
  }

  float acc[8] = {0, 0, 0, 0, 0, 0, 0, 0};
  for (int k4 = 0; k4 < D_K / 4; ++k4) {
    float4 v = centT4[(size_t)k4 * NCLUST + c];
#pragma unroll
    for (int q = 0; q < 8; ++q) {
      float4 r = *reinterpret_cast<const float4*>(&inp[q * D_K + k4 * 4]);  // uniform addr
      acc[q] += v.x * r.x + v.y * r.y + v.z * r.z + v.w * r.w;
    }
  }
#pragma unroll
  for (int q = 0; q < 8; ++q) lgs[q][c] = acc[q] * 10.0f;  // /TEMPERATURE
  __syncthreads();

  int wave = c >> 6, lane = c & 63;
#pragma unroll
  for (int qq = 0; qq < 2; ++qq) {
    int q = wave * 2 + qq;
    float4 lv = *reinterpret_cast<const float4*>(&lgs[q][lane * 4]);
    float m = fmaxf(fmaxf(lv.x, lv.y), fmaxf(lv.z, lv.w));
#pragma unroll
    for (int off = 32; off > 0; off >>= 1) m = fmaxf(m, __shfl_xor(m, off));
    float e0 = expf(lv.x - m), e1 = expf(lv.y - m), e2 = expf(lv.z - m), e3 = expf(lv.w - m);
    float s = e0 + e1 + e2 + e3;
#pragma unroll
    for (int off = 32; off > 0; off >>= 1) s += __shfl_xor(s, off);
    float thr = 0.01f * s;
    bool a0 = e0 > thr, a1 = e1 > thr, a2 = e2 > thr, a3 = e3 > thr;
    if (a0) cmask[lane * 4 + 0] = 1.0f;  // benign races: all writers store 1.0
    if (a1) cmask[lane * 4 + 1] = 1.0f;
    if (a2) cmask[lane * 4 + 2] = 1.0f;
    if (a3) cmask[lane * 4 + 3] = 1.0f;
    unsigned long long any = __ballot(a0 | a1 | a2 | a3);
    if (lane == 0) qmask[q0 + q] = any ? 1.0f : 0.0f;
  }
}

// Pipelined masked bf16 GEMM: 256x256, BK=32, 8 waves, 3-deep LDS ring,
// counted vmcnt(4), swizzled LDS (XOR kgroup with (row>>1)&3 via pre-swizzled
// global source + swizzled ds_read), setprio around MFMA clusters.
__global__ __launch_bounds__(512, 2) void gemm_masked_kernel(
    const ushort* __restrict__ A, const ushort* __restrict__ W,
    const float* __restrict__ bias, const int* __restrict__ assign,
    const float* __restrict__ qmask, const float* __restrict__ cmask,
    float* __restrict__ C) {
  __shared__ ushort sA[3][BM * BK];  // 3 x 16 KiB
  __shared__ ushort sB[3][BN * BK];  // 3 x 16 KiB   -> 96 KiB total

  int tid = threadIdx.x;
  int wave = tid >> 6, lane = tid & 63;

  // XCD N-partition: XCD x owns ntiles [8x, 8x+8) for all 16 mtiles ->
  // 2 MB W-panel L2-resident per XCD, W fetched from HBM once. 1024 % 8 == 0.
  int bid = blockIdx.x;
  int ntile = (bid & 7) * 8 + ((bid >> 3) & 7);  // 0..63
  int mtile = bid >> 6;                          // 0..15
  int m0 = mtile * BM, n0 = ntile * BN;

  int wr = wave >> 2, wc = wave & 3;  // 2x4 wave grid; per-wave C: 128x64

  const ushort* gA = A + (size_t)m0 * D_K;
  const ushort* gB = W + (size_t)n0 * D_K;

  // staging: per K-tile per operand = 256 rows x 32 k x 2B = 16 KB = 2 ops x (512thr x 16B)
  // LDS slot (row, kg) <- global (row, kg ^ ((row>>1)&3)); note ((128+row)>>1)&3 == ((row>>1)&3)
  int srow = tid >> 2;        // 0..127 (op adds +128)
  int kg = tid & 3;
  int ks = (kg ^ ((srow >> 1) & 3)) * 8;  // bf16 element offset of swizzled source group
  const ushort* srcA0 = gA + (size_t)srow * D_K + ks;
  const ushort* srcA1 = gA + (size_t)(128 + srow) * D_K + ks;
  const ushort* srcB0 = gB + (size_t)srow * D_K + ks;
  const ushort* srcB1 = gB + (size_t)(128 + srow) * D_K + ks;
  int ldso = wave * 512;  // ushort offset of this wave's 1KB chunk within an op region

#define STAGE(buf, kt) do {                              \
    GLOAD_LDS16(srcA0 + (kt), &sA[buf][ldso]);           \
    GLOAD_LDS16(srcA1 + (kt), &sA[buf][4096 + ldso]);    \
    GLOAD_LDS16(srcB0 + (kt), &sB[buf][ldso]);           \
    GLOAD_LDS16(srcB1 + (kt), &sB[buf][4096 + ldso]);    \
  } while (0)

  // fragment read indices (swizzled): elem (r, kg0*8..+8) at r*32 + (kg0^((r>>1)&3))*8
  int kg0 = lane >> 4, l15 = lane & 15;
  int aIdx[8], bIdx[4];
#pragma unroll
  for (int m = 0; m < 8; ++m) {
    int r = wr * 128 + m * 16 + l15;
    aIdx[m] = r * 32 + ((kg0 ^ ((r >> 1) & 3)) << 3);
  }
#pragma unroll
  for (int n = 0; n < 4; ++n) {
    int r = wc * 64 + n * 16 + l15;
    bIdx[n] = r * 32 + ((kg0 ^ ((r >> 1) & 3)) << 3);
  }

  f32x4 acc[8][4] = {};

  STAGE(0, 0);
  STAGE(1, BK);

#pragma unroll
  for (int t = 0; t < NT; ++t) {
    // entry: tile t landed (all but last 4 loads = tile t+1 may fly); workgroup aligned
    if (t < NT - 1) { WAIT_BAR(4); } else { WAIT_BAR(0); }
    if (t + 2 < NT) STAGE((t + 2) % 3, (t + 2) * BK);  // overwrites buf read in iter t-1: retired

    const ushort* sa = sA[t % 3];
    const ushort* sb = sB[t % 3];
    bf16x8 bf[4], af[4], af2[4];
#pragma unroll
    for (int n = 0; n < 4; ++n) bf[n] = *reinterpret_cast<const bf16x8*>(&sb[bIdx[n]]);
#pragma unroll
    for (int m = 0; m < 4; ++m) af[m] = *reinterpret_cast<const bf16x8*>(&sa[aIdx[m]]);
    __builtin_amdgcn_s_setprio(1);
#pragma unroll
    for (int m = 0; m < 4; ++m)
#pragma unroll
      for (int n = 0; n < 4; ++n)
        acc[m][n] = __builtin_amdgcn_mfma_f32_16x16x32_bf16(af[m], bf[n], acc[m][n], 0, 0, 0);
    __builtin_amdgcn_s_setprio(0);
#pragma unroll
    for (int m = 0; m < 4; ++m) af2[m] = *reinterpret_cast<const bf16x8*>(&sa[aIdx[4 + m]]);
    __builtin_amdgcn_s_setprio(1);
#pragma unroll
    for (int m = 0; m < 4; ++m)
#pragma unroll
      for (int n = 0; n < 4; ++n)
        acc[4 + m][n] = __builtin_amdgcn_mfma_f32_16x16x32_bf16(af2[m], bf[n], acc[4 + m][n], 0, 0, 0);
    __builtin_amdgcn_s_setprio(0);
  }
#undef STAGE

  // epilogue: C/D layout col=lane&15, row=(lane>>4)*4+reg (verified round 1)
  int lr = lane >> 4;
  float4 qm4[8];
#pragma unroll
  for (int m = 0; m < 8; ++m)
    qm4[m] = *reinterpret_cast<const float4*>(&qmask[m0 + wr * 128 + m * 16 + lr * 4]);
#pragma unroll
  for (int n = 0; n < 4; ++n) {
    int col = n0 + wc * 64 + n * 16 + l15;
    float bj = bias[col];
    float rm = cmask[assign[col]];
#pragma unroll
    for (int m = 0; m < 8; ++m) {
      size_t rbase = (size_t)(m0 + wr * 128 + m * 16 + lr * 4);
      C[(rbase + 0) * D_OUT + col] = (acc[m][n][0] + bj) * qm4[m].x * rm;
      C[(rbase + 1) * D_OUT + col] = (acc[m][n][1] + bj) * qm4[m].y * rm;
      C[(rbase + 2) * D_OUT + col] = (acc[m][n][2] + bj) * qm4[m].z * rm;
      C[(rbase + 3) * D_OUT + col] = (acc[m][n][3] + bj) * qm4[m].w * rm;
    }
  }
}

extern "C" void kernel_launch(void* const* d_in, const int* in_sizes, int n_in,
                              void* d_out, int out_size, void* d_ws, size_t ws_size,
                              hipStream_t stream) {
  const float* input     = (const float*)d_in[0];
  const float* weight    = (const float*)d_in[1];
  const float* bias      = (const float*)d_in[2];
  const float* centroids = (const float*)d_in[3];
  const int*   assign    = (const int*)d_in[4];
  float* out = (float*)d_out;

  // ws layout (bytes):
  //   A_bf16 : 0          (4 MiB)
  //   W_bf16 : 4,194,304  (16 MiB)
  //   qmask  : 20,971,520 (16 KB)
  //   cmask  : 20,987,904 (1 KB)
  //   centT4 : 21,000,192 (512 KB)
  char* ws = (char*)d_ws;
  ushort* A_bf   = (ushort*)ws;
  ushort* W_bf   = (ushort*)(ws + 4194304);
  float*  qmask  = (float*)(ws + 20971520);
  float*  cmask  = (float*)(ws + 20987904);
  float4* centT4 = (float4*)(ws + 21000192);

  cvt_bf16_kernel<<<(D_OUT * D_K / 8 + 255) / 256, 256, 0, stream>>>(weight, W_bf, D_OUT * D_K / 8);
  transpose_cent_kernel<<<128, 256, 0, stream>>>(centroids, centT4, cmask);
  routing_kernel<<<N_Q / 8, 256, 0, stream>>>(input, centT4, qmask, cmask, A_bf);
  gemm_masked_kernel<<<(N_Q / BM) * (D_OUT / BN), 512, 0, stream>>>(
      A_bf, W_bf, bias, assign, qmask, cmask, out);
}